// Round 4
// baseline (151.902 us; speedup 1.0000x reference)
//
#include <hip/hip_runtime.h>
#include <hip/hip_bf16.h>
#include <stdint.h>

// ===================================================================
// PriorLayer online BP scan, round 4.
// R3 post-mortem: putting the shuffle (ds_bpermute) chains BEFORE the
// MFMA ds_reads regressed 0.5us/step — the LDS pipe completes IN-ORDER
// within a wave, so the B-fragment reads waited out the bpermute chain.
// Reverted to R2 body ordering.
// Core R4 change: per-step time has been pinned at ~2us (~4800cyc)
// across R1-R3 while the instruction chain is ~600cyc — with 1 block/CU
// and a barrier per step, NOTHING hides the exposed memory/skew latency.
// => 2 blocks per CU (NBLK=512, CLEN=8, STEPS=16): two independent
// step-chains interleave on each CU, halving exposed latency per step.
// VGPR 72 <= 128 and LDS 2x18.9KB guarantee both blocks resident.
// Kept from R3 (mechanically sound VALU trims): 2^-6 folded into A
// (exact bf16 exponent shift), v_perm round-half-up bf16 state pack,
// BURN=8 (absmax floor is bf16 state quantization, not truncation).
// ===================================================================

#define DIM   256
#define SEQ   65536
#define G     16                    // chunks (MFMA columns) per block
#define NBLK  512                   // 2 blocks / CU
#define CLEN  (SEQ / (G * NBLK))    // 8 output steps per chunk
#define BURN  8
#define STEPS (BURN + CLEN)         // 16 (even — loop pairing relies on it)
#define NW    8
#define TPB   (NW * 64)
#define SROW  264                   // padded LDS row stride (bf16 elems)

typedef short bf16x8 __attribute__((ext_vector_type(8)));
typedef float f32x4  __attribute__((ext_vector_type(4)));
typedef float f32x2  __attribute__((ext_vector_type(2)));

static __device__ __forceinline__ unsigned short f2bf(float x) {
  __hip_bfloat16 h = __float2bfloat16(x);
  return *reinterpret_cast<unsigned short*>(&h);
}

// LDS-only barrier: drain lgkm (ds ops) but NOT vmcnt — global stores
// and prefetch loads stay in flight across the step boundary.
static __device__ __forceinline__ void lds_barrier() {
  asm volatile("s_waitcnt lgkmcnt(0)" ::: "memory");
  __builtin_amdgcn_s_barrier();
}

// pack two f32 to two bf16 (round-half-up): dword = [lo16=hi(a), hi16=hi(b)]
static __device__ __forceinline__ uint32_t pack_bf2(float a, float b) {
  uint32_t ua = __float_as_uint(a) + 0x8000u;
  uint32_t ub = __float_as_uint(b) + 0x8000u;
  return __builtin_amdgcn_perm(ub, ua, 0x07060302u);  // ua.b23 | ub.b23
}

__global__ __launch_bounds__(TPB, 4)
void prior_scan_kernel(const float* __restrict__ probs,
                       const float* __restrict__ tp,
                       float* __restrict__ out) {
  __shared__ __attribute__((aligned(16))) short S_T[2][G][SROW];
  __shared__ f32x2 pZL[2][NW][G];   // per-wave {sum q, sum q ln q} per col

  const int tid  = threadIdx.x;
  const int w    = tid >> 6;
  const int lane = tid & 63;
  const int n    = lane & 15;       // MFMA col = chunk within block
  const int quad = lane >> 4;
  const int c0   = blockIdx.x * G + n;          // this lane's chunk id
  const int r0 = (2 * w) * 16 + quad * 4;       // C/D row base, tile 0
  const int r1 = (2 * w + 1) * 16 + quad * 4;   // tile 1

  // ---- A-fragments of T * 2^-6: A[m=lane&15][k=quad*8+j], row=(2w+rt)*16+m
  bf16x8 A[2][8];
#pragma unroll
  for (int rt = 0; rt < 2; rt++) {
    const int row = (2 * w + rt) * 16 + n;
#pragma unroll
    for (int kb = 0; kb < 8; kb++) {
      const float* p = tp + row * DIM + kb * 32 + quad * 8;
      f32x4 f0 = *reinterpret_cast<const f32x4*>(p);
      f32x4 f1 = *reinterpret_cast<const f32x4*>(p + 4);
      bf16x8 a;
#pragma unroll
      for (int j = 0; j < 4; j++) {
        a[j]     = (short)f2bf(f0[j] * 0.015625f);
        a[4 + j] = (short)f2bf(f1[j] * 0.015625f);
      }
      A[rt][kb] = a;
    }
  }

  // ---- init state buf 0 = uniform (any positive constant; scale-free)
  for (int i = tid; i < G * SROW; i += TPB)
    (&S_T[0][0][0])[i] = (short)0x3B80;

  auto loadp = [&](int s, int rbase) -> f32x4 {
    int t = c0 * CLEN - BURN + s;
    if (t < 0) t = 0;               // value unused while state clamped
    return *reinterpret_cast<const f32x4*>(probs + (size_t)t * DIM + rbase);
  };

  f32x4 pf[2][2];
  pf[0][0] = loadp(0, r0); pf[0][1] = loadp(0, r1);
  pf[1][0] = loadp(1, r0); pf[1][1] = loadp(1, r1);

  lds_barrier();

  float qp[2][4];                   // q of previous step (deferred norm)

  // R2 ordering: recurrence for `step`; partials (shuffles) AFTER the
  // MFMAs; finalize (normalize + H) for step-1 off the serial chain.
  auto body = [&](int step, int cur, int nxt) {
    float q[2][4];
    if (step < STEPS) {
      // --- recurrence: acc = (2^-6 T) @ u  (B[k][n] from S_T[cur])
      f32x4 acc0 = {0.f, 0.f, 0.f, 0.f}, acc1 = {0.f, 0.f, 0.f, 0.f};
#pragma unroll
      for (int kb = 0; kb < 8; kb++) {
        bf16x8 b = *reinterpret_cast<const bf16x8*>(
            &S_T[cur][n][kb * 32 + quad * 8]);
        acc0 = __builtin_amdgcn_mfma_f32_16x16x32_bf16(A[0][kb], b, acc0, 0, 0, 0);
        acc1 = __builtin_amdgcn_mfma_f32_16x16x32_bf16(A[1][kb], b, acc1, 0, 0, 0);
      }
      const int t = c0 * CLEN - BURN + step;
      float sz = 0.f, sl = 0.f;
#pragma unroll
      for (int rt = 0; rt < 2; rt++) {
        f32x4 p = pf[cur][rt];
        f32x4 a = rt ? acc1 : acc0;
#pragma unroll
        for (int v = 0; v < 4; v++) {
          float qq = a[v] * p[v];   // C/D: row = quad*4+v, col = n
          q[rt][v] = qq;
          sz += qq;
          sl += qq * __logf(qq + 1e-30f);
        }
      }
      // --- state write (bf16 pack; clamp pre-start chunk 0)
#pragma unroll
      for (int rt = 0; rt < 2; rt++) {
        uint2 sp;
        if (t < 0) {
          sp.x = sp.y = 0x3B803B80u;
        } else {
          sp.x = pack_bf2(q[rt][0], q[rt][1]);
          sp.y = pack_bf2(q[rt][2], q[rt][3]);
        }
        *reinterpret_cast<uint2*>(&S_T[nxt][n][rt ? r1 : r0]) = sp;
      }
      // --- wave partials for this step's Z / entropy
      sz += __shfl_xor(sz, 16); sz += __shfl_xor(sz, 32);
      sl += __shfl_xor(sl, 16); sl += __shfl_xor(sl, 32);
      if (lane < 16) pZL[cur][w][n] = f32x2{sz, sl};
    }

    // --- finalize step-1: reduce partials (slot nxt == (step-1)&1),
    //     write normalized probs + entropy. Off the serial chain.
    if (step >= BURN + 1) {
      float Z = 0.f, L = 0.f;
#pragma unroll
      for (int ww = 0; ww < NW; ww++) {
        f32x2 v = pZL[nxt][ww][n];
        Z += v[0]; L += v[1];
      }
      const float zi = __builtin_amdgcn_rcpf(Z);
      const int t1 = c0 * CLEN + (step - 1 - BURN);
#pragma unroll
      for (int rt = 0; rt < 2; rt++) {
        f32x4 o;
#pragma unroll
        for (int v = 0; v < 4; v++) o[v] = qp[rt][v] * zi;
        *reinterpret_cast<f32x4*>(out + (size_t)t1 * DIM + (rt ? r1 : r0)) = o;
      }
      if (tid < 16)                 // n == tid for these lanes
        out[(size_t)SEQ * DIM + t1] = __logf(Z) - L * zi;
    }

    if (step < STEPS) {
      // --- carry q; prefetch step+2 into the consumed slot
#pragma unroll
      for (int rt = 0; rt < 2; rt++)
#pragma unroll
        for (int v = 0; v < 4; v++) qp[rt][v] = q[rt][v];
      int ps = step + 2; if (ps > STEPS - 1) ps = STEPS - 1;
      pf[cur][0] = loadp(ps, r0);
      pf[cur][1] = loadp(ps, r1);
      lds_barrier();
    }
  };

  for (int s = 0; s < STEPS; s += 2) {
    body(s, 0, 1);
    body(s + 1, 1, 0);
  }
  body(STEPS, 0, 1);                // reduction-only tail (STEPS even)
}

extern "C" void kernel_launch(void* const* d_in, const int* in_sizes, int n_in,
                              void* d_out, int out_size, void* d_ws, size_t ws_size,
                              hipStream_t stream) {
  const float* probs = (const float*)d_in[0];   // (65536, 256)
  const float* tp    = (const float*)d_in[1];   // (256, 256)
  float* out         = (float*)d_out;           // 65536*256 probs + 65536 H

  hipLaunchKernelGGL(prior_scan_kernel, dim3(NBLK), dim3(TPB), 0, stream,
                     probs, tp, out);
}

// Round 5
// 141.754 us; speedup vs baseline: 1.0716x; 1.0716x over previous
//
#include <hip/hip_runtime.h>
#include <hip/hip_bf16.h>
#include <stdint.h>

// ===================================================================
// PriorLayer online BP scan, round 5.
// R4 post-mortem: 2 co-resident blocks/CU gave ZERO overlap — per-CU
// wall = (fixed ~4800cyc per step) x (serial block-steps per CU),
// invariant across R1-R4 tail restructures. The only lever that works
// is cutting serial step count.
// R5: G=32 columns per block, 1 block/CU (NBLK=256), CLEN=8, BURN=8,
// STEPS=16 -> half the serial steps of R4 at identical total math
// (numerically bit-identical chunking to R4: 8192 chunks x 8 x 8).
// Each wave: 2 row-tiles x 2 col-tiles of the VERIFIED 16x16x32 bf16
// MFMA (32 MFMA/step/wave); B-frag read once per (kb, col-tile) and
// shared across row-tiles. Body keeps the validated R2 ordering
// (shuffles AFTER the MFMA ds_reads; finalize one step behind).
// ===================================================================

#define DIM   256
#define SEQ   65536
#define G     32                    // chunks (MFMA columns) per block
#define NBLK  256                   // 1 block / CU
#define CLEN  (SEQ / (G * NBLK))    // 8 output steps per chunk
#define BURN  8
#define STEPS (BURN + CLEN)         // 16 (even — loop pairing relies on it)
#define NW    8
#define TPB   (NW * 64)
#define SROW  264                   // padded LDS row stride (bf16 elems)

typedef short bf16x8 __attribute__((ext_vector_type(8)));
typedef float f32x4  __attribute__((ext_vector_type(4)));
typedef float f32x2  __attribute__((ext_vector_type(2)));

static __device__ __forceinline__ unsigned short f2bf(float x) {
  __hip_bfloat16 h = __float2bfloat16(x);
  return *reinterpret_cast<unsigned short*>(&h);
}

// LDS-only barrier: drain lgkm (ds ops) but NOT vmcnt — global stores
// and prefetch loads stay in flight across the step boundary.
static __device__ __forceinline__ void lds_barrier() {
  asm volatile("s_waitcnt lgkmcnt(0)" ::: "memory");
  __builtin_amdgcn_s_barrier();
}

// pack two f32 to two bf16 (round-half-up): dword = [lo16=hi(a), hi16=hi(b)]
static __device__ __forceinline__ uint32_t pack_bf2(float a, float b) {
  uint32_t ua = __float_as_uint(a) + 0x8000u;
  uint32_t ub = __float_as_uint(b) + 0x8000u;
  return __builtin_amdgcn_perm(ub, ua, 0x07060302u);  // ua.b23 | ub.b23
}

__global__ __launch_bounds__(TPB)
void prior_scan_kernel(const float* __restrict__ probs,
                       const float* __restrict__ tp,
                       float* __restrict__ out) {
  __shared__ __attribute__((aligned(16))) short S_T[2][G][SROW];
  __shared__ f32x2 pZL[2][NW][G];   // per-wave {sum q, sum q ln q} per col

  const int tid  = threadIdx.x;
  const int w    = tid >> 6;
  const int lane = tid & 63;
  const int n    = lane & 15;       // MFMA col within col-tile
  const int quad = lane >> 4;
  const int cbase = blockIdx.x * G;
  const int r0 = (2 * w) * 16 + quad * 4;       // C/D row base, tile 0
  const int r1 = (2 * w + 1) * 16 + quad * 4;   // tile 1

  // ---- A-fragments of T * 2^-6: A[m=lane&15][k=quad*8+j], row=(2w+rt)*16+m
  bf16x8 A[2][8];
#pragma unroll
  for (int rt = 0; rt < 2; rt++) {
    const int row = (2 * w + rt) * 16 + n;
#pragma unroll
    for (int kb = 0; kb < 8; kb++) {
      const float* p = tp + row * DIM + kb * 32 + quad * 8;
      f32x4 f0 = *reinterpret_cast<const f32x4*>(p);
      f32x4 f1 = *reinterpret_cast<const f32x4*>(p + 4);
      bf16x8 a;
#pragma unroll
      for (int j = 0; j < 4; j++) {
        a[j]     = (short)f2bf(f0[j] * 0.015625f);
        a[4 + j] = (short)f2bf(f1[j] * 0.015625f);
      }
      A[rt][kb] = a;
    }
  }

  // ---- init state buf 0 = uniform (any positive constant; scale-free)
  for (int i = tid; i < G * SROW; i += TPB)
    (&S_T[0][0][0])[i] = (short)0x3B80;

  // observation fragment loader; ct selects the column-tile (n or n+16)
  auto loadp = [&](int s, int ct, int rbase) -> f32x4 {
    int t = (cbase + n + 16 * ct) * CLEN - BURN + s;
    if (t < 0) t = 0;               // value unused while state clamped
    return *reinterpret_cast<const f32x4*>(probs + (size_t)t * DIM + rbase);
  };

  f32x4 pf[2][2][2];                // [parity][ct][rt]
#pragma unroll
  for (int par = 0; par < 2; par++)
#pragma unroll
    for (int ct = 0; ct < 2; ct++) {
      pf[par][ct][0] = loadp(par, ct, r0);
      pf[par][ct][1] = loadp(par, ct, r1);
    }

  lds_barrier();

  float qp[2][2][4];                // [rt][ct][v], previous step's q

  auto body = [&](int step, int cur, int nxt) {
    float q[2][2][4];
    if (step < STEPS) {
      // --- recurrence: acc[rt][ct] = (2^-6 T) @ u  over both col-tiles
      f32x4 acc[2][2];
#pragma unroll
      for (int rt = 0; rt < 2; rt++)
#pragma unroll
        for (int ct = 0; ct < 2; ct++) acc[rt][ct] = f32x4{0.f, 0.f, 0.f, 0.f};
#pragma unroll
      for (int kb = 0; kb < 8; kb++) {
        bf16x8 b0 = *reinterpret_cast<const bf16x8*>(
            &S_T[cur][n][kb * 32 + quad * 8]);
        bf16x8 b1 = *reinterpret_cast<const bf16x8*>(
            &S_T[cur][n + 16][kb * 32 + quad * 8]);
        acc[0][0] = __builtin_amdgcn_mfma_f32_16x16x32_bf16(A[0][kb], b0, acc[0][0], 0, 0, 0);
        acc[1][0] = __builtin_amdgcn_mfma_f32_16x16x32_bf16(A[1][kb], b0, acc[1][0], 0, 0, 0);
        acc[0][1] = __builtin_amdgcn_mfma_f32_16x16x32_bf16(A[0][kb], b1, acc[0][1], 0, 0, 0);
        acc[1][1] = __builtin_amdgcn_mfma_f32_16x16x32_bf16(A[1][kb], b1, acc[1][1], 0, 0, 0);
      }
      int   tt[2];
      float sz[2] = {0.f, 0.f}, sl[2] = {0.f, 0.f};
#pragma unroll
      for (int ct = 0; ct < 2; ct++)
        tt[ct] = (cbase + n + 16 * ct) * CLEN - BURN + step;
#pragma unroll
      for (int ct = 0; ct < 2; ct++)
#pragma unroll
        for (int rt = 0; rt < 2; rt++) {
          f32x4 p = pf[cur][ct][rt];
          f32x4 a = acc[rt][ct];
#pragma unroll
          for (int v = 0; v < 4; v++) {
            float qq = a[v] * p[v]; // C/D: row = quad*4+v, col = n(+16ct)
            q[rt][ct][v] = qq;
            sz[ct] += qq;
            sl[ct] += qq * __logf(qq + 1e-30f);
          }
        }
      // --- state write (bf16 pack; clamp pre-start chunk 0)
#pragma unroll
      for (int ct = 0; ct < 2; ct++)
#pragma unroll
        for (int rt = 0; rt < 2; rt++) {
          uint2 sp;
          if (tt[ct] < 0) {
            sp.x = sp.y = 0x3B803B80u;
          } else {
            sp.x = pack_bf2(q[rt][ct][0], q[rt][ct][1]);
            sp.y = pack_bf2(q[rt][ct][2], q[rt][ct][3]);
          }
          *reinterpret_cast<uint2*>(&S_T[nxt][n + 16 * ct][rt ? r1 : r0]) = sp;
        }
      // --- wave partials for this step's Z / entropy (both col-tiles)
#pragma unroll
      for (int ct = 0; ct < 2; ct++) {
        sz[ct] += __shfl_xor(sz[ct], 16); sz[ct] += __shfl_xor(sz[ct], 32);
        sl[ct] += __shfl_xor(sl[ct], 16); sl[ct] += __shfl_xor(sl[ct], 32);
      }
      if (lane < 16) {
        pZL[cur][w][n]      = f32x2{sz[0], sl[0]};
        pZL[cur][w][n + 16] = f32x2{sz[1], sl[1]};
      }
    }

    // --- finalize step-1: reduce partials (slot nxt == (step-1)&1),
    //     write normalized probs + entropy. Off the serial chain.
    if (step >= BURN + 1) {
#pragma unroll
      for (int ct = 0; ct < 2; ct++) {
        const int col = n + 16 * ct;
        float Z = 0.f, L = 0.f;
#pragma unroll
        for (int ww = 0; ww < NW; ww++) {
          f32x2 v = pZL[nxt][ww][col];
          Z += v[0]; L += v[1];
        }
        const float zi = __builtin_amdgcn_rcpf(Z);
        const int t1 = (cbase + col) * CLEN + (step - 1 - BURN);
#pragma unroll
        for (int rt = 0; rt < 2; rt++) {
          f32x4 o;
#pragma unroll
          for (int v = 0; v < 4; v++) o[v] = qp[rt][ct][v] * zi;
          *reinterpret_cast<f32x4*>(out + (size_t)t1 * DIM + (rt ? r1 : r0)) = o;
        }
      }
      if (tid < 32) {               // col == tid for these lanes
        float Z = 0.f, L = 0.f;
#pragma unroll
        for (int ww = 0; ww < NW; ww++) {
          f32x2 v = pZL[nxt][ww][tid];
          Z += v[0]; L += v[1];
        }
        const float zi = __builtin_amdgcn_rcpf(Z);
        const int t1 = (cbase + tid) * CLEN + (step - 1 - BURN);
        out[(size_t)SEQ * DIM + t1] = __logf(Z) - L * zi;
      }
    }

    if (step < STEPS) {
      // --- carry q; prefetch step+2 into the consumed slot
#pragma unroll
      for (int ct = 0; ct < 2; ct++)
#pragma unroll
        for (int rt = 0; rt < 2; rt++)
#pragma unroll
          for (int v = 0; v < 4; v++) qp[rt][ct][v] = q[rt][ct][v];
      int ps = step + 2; if (ps > STEPS - 1) ps = STEPS - 1;
#pragma unroll
      for (int ct = 0; ct < 2; ct++) {
        pf[cur][ct][0] = loadp(ps, ct, r0);
        pf[cur][ct][1] = loadp(ps, ct, r1);
      }
      lds_barrier();
    }
  };

  for (int s = 0; s < STEPS; s += 2) {
    body(s, 0, 1);
    body(s + 1, 1, 0);
  }
  body(STEPS, 0, 1);                // reduction-only tail (STEPS even)
}

extern "C" void kernel_launch(void* const* d_in, const int* in_sizes, int n_in,
                              void* d_out, int out_size, void* d_ws, size_t ws_size,
                              hipStream_t stream) {
  const float* probs = (const float*)d_in[0];   // (65536, 256)
  const float* tp    = (const float*)d_in[1];   // (256, 256)
  float* out         = (float*)d_out;           // 65536*256 probs + 65536 H

  hipLaunchKernelGGL(prior_scan_kernel, dim3(NBLK), dim3(TPB), 0, stream,
                     probs, tp, out);
}